// Round 5
// baseline (139.932 us; speedup 1.0000x reference)
//
#include <hip/hip_runtime.h>

// ---------------------------------------------------------------------------
// HR2HK: H[k, N*13, N*13] from edge/node features, Hermitian fold-in.
// SINGLE-KERNEL fast path: one block per (k-group, output row). Each block
//   1) zeros a KB-row LDS buffer,
//   2) scans edge_index directly (no CSR / no prep kernels) building a packed
//      local incident-edge list,
//   3) adds the symmetrized diagonal,
//   4) computes per-(edge,k) phases and scatter-adds 13-wide segments via LDS
//      atomics -- each hop load amortized over KB k-points,
//   5) streams the finished rows to global with coalesced float4 stores
//      (every output byte written exactly once).
// Dual layout keyed off out_size (proven round 3):
//   out_size >= 2*K*DIM^2 : interleaved complex64 ; else real-part-only f32.
// Overflow (absurd node degree) -> correct in-block slow path.
// Guard failure -> verified round-3 3-kernel fallback.
// ---------------------------------------------------------------------------

// orbital structure: l = [0,0,1,1,2], sizes {1,1,3,3,5}, offsets {0,1,2,5,8}
__device__ __forceinline__ void orb_of(int r, int& i, int& ri, int& nv) {
    if (r < 1)      { i = 0; ri = r;     nv = 1; }
    else if (r < 2) { i = 1; ri = r - 1; nv = 1; }
    else if (r < 5) { i = 2; ri = r - 2; nv = 3; }
    else if (r < 8) { i = 3; ri = r - 5; nv = 3; }
    else            { i = 4; ri = r - 8; nv = 5; }
}
__device__ __forceinline__ int offs_of(int i) {
    return i == 0 ? 0 : (i == 1 ? 1 : (i == 2 ? 2 : (i == 3 ? 5 : 8)));
}
__device__ __forceinline__ int rowstart_of(int i) {   // {0,13,25,58,82}
    return i == 0 ? 0 : (i == 1 ? 13 : (i == 2 ? 25 : (i == 3 ? 58 : 82)));
}
__device__ __forceinline__ int pmap(int r, int c) {
    int i, ri, nvi, j, cj, nvj;
    orb_of(r, i, ri, nvi);
    orb_of(c, j, cj, nvj);
    return 13 * offs_of(i) + nvi * offs_of(j) + ri * nvj + cj;
}
__device__ __forceinline__ int nmap(int r, int c) {
    int i, ri, nvi, j, cj, nvj;
    orb_of(r, i, ri, nvi);
    orb_of(c, j, cj, nvj);
    if (i <= j)
        return rowstart_of(i) + nvi * (offs_of(j) - offs_of(i)) + ri * nvj + cj;
    else
        return rowstart_of(j) + nvj * (offs_of(i) - offs_of(j)) + cj * nvi + ri;
}

constexpr int MAXBUF = 10400;   // floats; KB*rowf must fit (real KB=4, cplx KB=2)
constexpr int CAP    = 1024;    // per-block incident-entry list capacity
constexpr int PCH    = 256;     // process sub-chunk (entries)
constexpr float TWO_PI = 6.28318530717958647692f;

// ============================ main fused kernel ============================
template <int CPLX, int KB>
__global__ __launch_bounds__(256) void hr2hk_kernel(const float* __restrict__ ef,
                                                    const float* __restrict__ nf,
                                                    const float* __restrict__ kp,
                                                    const float* __restrict__ ecs,
                                                    const int*   __restrict__ eidx,
                                                    float* __restrict__ out,
                                                    int N, int E, int K) {
    const int DIM  = N * 13;
    const int rowf = CPLX ? DIM * 2 : DIM;   // floats per output row
    const int row4 = rowf >> 2;              // guarded: rowf % 4 == 0
    const int a  = blockIdx.x % DIM;         // output row within a k-slice
    const int kg = blockIdx.x / DIM;         // k-group
    const int n1 = a / 13, r = a - n1 * 13;
    const int k0 = kg * KB;
    const int kb = (K - k0 < KB) ? (K - k0) : KB;
    const int tid = threadIdx.x;

    __shared__ float buf[MAXBUF];
    __shared__ int   list[CAP];
    __shared__ float ph[PCH * KB * (CPLX ? 2 : 1)];   // 1024 floats either way
    __shared__ int   pm_src[13], pm_dst[13];
    __shared__ int   cnt_sh;

    // 1) zero the row buffers
    float4* b4 = (float4*)buf;
    const float4 z = {0.f, 0.f, 0.f, 0.f};
    for (int t = tid; t < kb * row4; t += 256) b4[t] = z;
    if (tid < 13) { pm_src[tid] = pmap(r, tid); pm_dst[tid] = pmap(tid, r); }
    if (tid == 0) cnt_sh = 0;
    __syncthreads();

    // 2) scan all edges, build packed local list: (other<<16)|(e<<1)|is_dst
    for (int e = tid; e < E; e += 256) {
        int s = eidx[e], d = eidx[E + e];
        if (s == n1) {
            int p = atomicAdd(&cnt_sh, 1);
            if (p < CAP) list[p] = (d << 16) | (e << 1);
        }
        if (d == n1) {
            int p = atomicAdd(&cnt_sh, 1);
            if (p < CAP) list[p] = (s << 16) | (e << 1) | 1;
        }
    }
    __syncthreads();
    const int cnt = cnt_sh;

    // 3) symmetrized diagonal (atomic: may collide with self-loop edges)
    if (tid < 13) {
        float v = 0.5f * (nf[n1 * 107 + nmap(r, tid)] + nf[n1 * 107 + nmap(tid, r)]);
        int col = n1 * 13 + tid;
        for (int kk = 0; kk < kb; ++kk) {
            if (CPLX) atomicAdd(&buf[kk * rowf + col * 2], v);
            else      atomicAdd(&buf[kk * rowf + col], v);
        }
    }

    if (cnt <= CAP) {
        // 4) process entries in sub-chunks: phases then 13-wide scatter
        for (int lb = 0; lb < cnt; lb += PCH) {
            int cc = min(PCH, cnt - lb);
            for (int t = tid; t < cc * KB; t += 256) {
                int li = t / KB, kk = t - li * KB;
                if (kk < kb) {
                    int e = ((unsigned)list[lb + li] >> 1) & 0x7fff;
                    float sx = ecs[e * 3], sy = ecs[e * 3 + 1], sz = ecs[e * 3 + 2];
                    int k = k0 + kk;
                    float dot = kp[k * 3] * sx + kp[k * 3 + 1] * sy + kp[k * 3 + 2] * sz;
                    float th = TWO_PI * dot;
                    if (CPLX) {
                        float sn, co;
                        sincosf(th, &sn, &co);
                        ph[(li * KB + kk) * 2]     = co;
                        ph[(li * KB + kk) * 2 + 1] = sn;
                    } else {
                        ph[li * KB + kk] = cosf(th);
                    }
                }
            }
            __syncthreads();
            for (int t = tid; t < cc * 13; t += 256) {
                int li = t / 13, c = t - li * 13;
                int entry = list[lb + li];
                int e     = ((unsigned)entry >> 1) & 0x7fff;
                int flag  = entry & 1;
                int other = (int)((unsigned)entry >> 16);
                float h = ef[e * 169 + (flag ? pm_dst[c] : pm_src[c])];
                int col = other * 13 + c;
                for (int kk = 0; kk < kb; ++kk) {
                    if (CPLX) {
                        float co = ph[(li * KB + kk) * 2];
                        float si = ph[(li * KB + kk) * 2 + 1];
                        atomicAdd(&buf[kk * rowf + col * 2],     h * co);
                        atomicAdd(&buf[kk * rowf + col * 2 + 1], flag ? h * si : -h * si);
                    } else {
                        atomicAdd(&buf[kk * rowf + col], h * ph[li * KB + kk]);
                    }
                }
            }
            __syncthreads();
        }
    } else {
        // degenerate-degree slow path (correct; effectively never taken)
        for (int e = 0; e < E; ++e) {
            int s = eidx[e], d = eidx[E + e];
            if (s != n1 && d != n1) continue;
            for (int t = tid; t < 2 * 13 * kb; t += 256) {
                int half = t / (13 * kb);
                int rem  = t - half * 13 * kb;
                int c = rem / kb, kk = rem - c * kb;
                if (half == 0 && s != n1) continue;
                if (half == 1 && d != n1) continue;
                int flag  = half;
                int other = half ? s : d;
                float sx = ecs[e * 3], sy = ecs[e * 3 + 1], sz = ecs[e * 3 + 2];
                int k = k0 + kk;
                float dot = kp[k * 3] * sx + kp[k * 3 + 1] * sy + kp[k * 3 + 2] * sz;
                float th = TWO_PI * dot;
                float h  = ef[e * 169 + (flag ? pm_dst[c] : pm_src[c])];
                int col = other * 13 + c;
                if (CPLX) {
                    float sn, co;
                    sincosf(th, &sn, &co);
                    atomicAdd(&buf[kk * rowf + col * 2],     h * co);
                    atomicAdd(&buf[kk * rowf + col * 2 + 1], flag ? h * sn : -h * sn);
                } else {
                    atomicAdd(&buf[kk * rowf + col], h * cosf(th));
                }
            }
        }
    }
    __syncthreads();

    // 5) stream kb finished rows out, coalesced float4, written exactly once
    for (int t = tid; t < kb * row4; t += 256) {
        int kk = t / row4, j = t - kk * row4;
        long base = ((long)(k0 + kk) * DIM + a) * (long)rowf;
        ((float4*)(out + base))[j] = b4[kk * row4 + j];
    }
}

// ====================== fallback path (round-3, verified) ==================

__global__ __launch_bounds__(256) void zero_kernel(float* __restrict__ out, long n) {
    long n4 = n >> 2;
    float4* out4 = (float4*)out;
    long i = (long)blockIdx.x * blockDim.x + threadIdx.x;
    long stride = (long)gridDim.x * blockDim.x;
    const float4 z = {0.f, 0.f, 0.f, 0.f};
    for (long t = i; t < n4; t += stride) out4[t] = z;
    if (i == 0) for (long j = n4 << 2; j < n; ++j) out[j] = 0.f;
}

template <int CPLX>
__global__ __launch_bounds__(256) void diag_kernel(const float* __restrict__ nf,
                                                   float* __restrict__ out,
                                                   int N, int total, long out_lim) {
    int t = blockIdx.x * blockDim.x + threadIdx.x;
    if (t >= total) return;
    int per_k = N * 169;
    int k = t / per_k, rem = t - k * per_k;
    int n = rem / 169, idx = rem - n * 169;
    int r = idx / 13, c = idx - r * 13;
    float v = 0.5f * (nf[n * 107 + nmap(r, c)] + nf[n * 107 + nmap(c, r)]);
    long DIM = (long)N * 13;
    long off = ((long)k * DIM + (long)n * 13 + r) * DIM + (long)n * 13 + c;
    if (CPLX) off *= 2;
    if (off >= 0 && off < out_lim) out[off] = v;
}

template <int CPLX>
__global__ __launch_bounds__(256) void edge_kernel(const float* __restrict__ ef,
                                                   const float* __restrict__ kp,
                                                   const float* __restrict__ ecs,
                                                   const int*   __restrict__ eidx,
                                                   float* __restrict__ out,
                                                   int N, int E, int K, long out_lim) {
    const int e = blockIdx.x;
    __shared__ float hop_sh[169];
    __shared__ float cos_sh[32];
    __shared__ float sin_sh[32];
    const int tid = threadIdx.x;
    const int r = tid / 13, c = tid - r * 13;

    if (tid < 169) hop_sh[tid] = ef[(long)e * 169 + pmap(r, c)];
    if (tid < K && tid < 32) {
        float sx = ecs[e * 3 + 0], sy = ecs[e * 3 + 1], sz = ecs[e * 3 + 2];
        float dot = kp[tid * 3 + 0] * sx + kp[tid * 3 + 1] * sy + kp[tid * 3 + 2] * sz;
        float th = TWO_PI * dot;
        float s, co;
        sincosf(th, &s, &co);
        cos_sh[tid] = co;
        sin_sh[tid] = s;
    }
    __syncthreads();
    if (tid >= 169) return;

    const int src = eidx[e];
    const int dst = eidx[E + e];
    const long DIM = (long)N * 13;
    const long SL  = DIM * DIM;
    const float h  = hop_sh[tid];
    const float ht = hop_sh[c * 13 + r];
    const long base1 = ((long)src * 13 + r) * DIM + (long)dst * 13 + c;
    const long base2 = ((long)dst * 13 + r) * DIM + (long)src * 13 + c;

    for (int k = 0; k < K; ++k) {
        float co = cos_sh[k & 31];
        float si = sin_sh[k & 31];
        if (CPLX) {
            long o1 = ((long)k * SL + base1) * 2;
            long o2 = ((long)k * SL + base2) * 2;
            if (o1 >= 0 && o1 + 1 < out_lim) {
                atomicAdd(out + o1,      h * co);
                atomicAdd(out + o1 + 1, -h * si);
            }
            if (o2 >= 0 && o2 + 1 < out_lim) {
                atomicAdd(out + o2,     ht * co);
                atomicAdd(out + o2 + 1, ht * si);
            }
        } else {
            long o1 = (long)k * SL + base1;
            long o2 = (long)k * SL + base2;
            if (o1 >= 0 && o1 < out_lim) atomicAdd(out + o1, h * co);
            if (o2 >= 0 && o2 < out_lim) atomicAdd(out + o2, ht * co);
        }
    }
}

// ================================ launch ===================================

extern "C" void kernel_launch(void* const* d_in, const int* in_sizes, int n_in,
                              void* d_out, int out_size, void* d_ws, size_t ws_size,
                              hipStream_t stream) {
    const float* ef   = (const float*)d_in[0];   // edge_features   (E, 169)
    const float* nf   = (const float*)d_in[1];   // node_features   (N, 107)
    const float* kp   = (const float*)d_in[2];   // kpoints         (K, 3)
    const float* ecs  = (const float*)d_in[3];   // edge_cell_shift (E, 3)
    const int*   eidx = (const int*)d_in[4];     // edge_index      (2, E)

    const int E = in_sizes[0] / 169;
    const int N = in_sizes[1] / 107;
    const int K = in_sizes[2] / 3;

    float* out = (float*)d_out;
    const long DIM  = (long)N * 13;
    const long SL   = DIM * DIM;
    const long full = (long)K * SL * 2;
    const int  cplx = ((long)out_size >= full) ? 1 : 0;
    const long out_lim = (long)out_size;

    const int rowf = (int)DIM * (cplx ? 2 : 1);
    const int KB   = cplx ? 2 : 4;
    const bool fast_ok = (E < 32768) && (N >= 1) && (N < 4096) &&
                         ((long)KB * rowf <= MAXBUF) && (rowf % 4 == 0) &&
                         ((long)out_size == (long)K * SL * (cplx ? 2 : 1));

    if (fast_ok) {
        const int kgroups = (K + KB - 1) / KB;
        const int grid = kgroups * (int)DIM;
        if (cplx)
            hr2hk_kernel<1, 2><<<grid, 256, 0, stream>>>(ef, nf, kp, ecs, eidx,
                                                         out, N, E, K);
        else
            hr2hk_kernel<0, 4><<<grid, 256, 0, stream>>>(ef, nf, kp, ecs, eidx,
                                                         out, N, E, K);
    } else {
        // verified round-3 fallback
        zero_kernel<<<2048, 256, 0, stream>>>(out, out_lim);
        int total_diag = K * N * 169;
        int blocks_diag = (total_diag + 255) / 256;
        if (cplx) {
            diag_kernel<1><<<blocks_diag, 256, 0, stream>>>(nf, out, N, total_diag, out_lim);
            edge_kernel<1><<<E, 256, 0, stream>>>(ef, kp, ecs, eidx, out, N, E, K, out_lim);
        } else {
            diag_kernel<0><<<blocks_diag, 256, 0, stream>>>(nf, out, N, total_diag, out_lim);
            edge_kernel<0><<<E, 256, 0, stream>>>(ef, kp, ecs, eidx, out, N, E, K, out_lim);
        }
    }
}

// Round 6
// 110.936 us; speedup vs baseline: 1.2614x; 1.2614x over previous
//
#include <hip/hip_runtime.h>

// ---------------------------------------------------------------------------
// HR2HK: H[k, N*13, N*13] from edge/node features, Hermitian fold-in.
// Two launches:
//  prep_all (1 block): CSR adjacency in LDS (count -> scan -> fill), packed
//    entries (other<<18)|(e<<1)|flag written to d_ws.
//  hr2hk_main (DIM blocks): block a=(n1,r) builds all K rows. Prologue stages
//    incident entries, hop 13-segments, and cnt*K phases in LDS ONCE; per k:
//    zero LDS row -> diag + LDS-atomic scatter -> coalesced float4 store.
//    Every output byte written exactly once; no global atomics.
// Dual layout keyed off out_size (proven round 3):
//   out_size >= 2*K*DIM^2 : interleaved complex64 ; else real-part-only f32.
// Guard failure -> verified round-3 3-kernel fallback.
// ---------------------------------------------------------------------------

// orbital structure: l = [0,0,1,1,2], sizes {1,1,3,3,5}, offsets {0,1,2,5,8}
__device__ __forceinline__ void orb_of(int r, int& i, int& ri, int& nv) {
    if (r < 1)      { i = 0; ri = r;     nv = 1; }
    else if (r < 2) { i = 1; ri = r - 1; nv = 1; }
    else if (r < 5) { i = 2; ri = r - 2; nv = 3; }
    else if (r < 8) { i = 3; ri = r - 5; nv = 3; }
    else            { i = 4; ri = r - 8; nv = 5; }
}
__device__ __forceinline__ int offs_of(int i) {
    return i == 0 ? 0 : (i == 1 ? 1 : (i == 2 ? 2 : (i == 3 ? 5 : 8)));
}
__device__ __forceinline__ int rowstart_of(int i) {   // {0,13,25,58,82}
    return i == 0 ? 0 : (i == 1 ? 13 : (i == 2 ? 25 : (i == 3 ? 58 : 82)));
}
__device__ __forceinline__ int pmap(int r, int c) {
    int i, ri, nvi, j, cj, nvj;
    orb_of(r, i, ri, nvi);
    orb_of(c, j, cj, nvj);
    return 13 * offs_of(i) + nvi * offs_of(j) + ri * nvj + cj;
}
__device__ __forceinline__ int nmap(int r, int c) {
    int i, ri, nvi, j, cj, nvj;
    orb_of(r, i, ri, nvi);
    orb_of(c, j, cj, nvj);
    if (i <= j)
        return rowstart_of(i) + nvi * (offs_of(j) - offs_of(i)) + ri * nvj + cj;
    else
        return rowstart_of(j) + nvj * (offs_of(i) - offs_of(j)) + cj * nvi + ri;
}

constexpr float TWO_PI = 6.28318530717958647692f;
constexpr int KMAX = 8;     // fast-path k limit (phase LDS sizing)
constexpr int CAPC = 128;   // staged incident-entry capacity per block

// ============================ prep: CSR in one block =======================
__global__ __launch_bounds__(1024) void prep_all(const int* __restrict__ eidx,
                                                 int* __restrict__ off_src,
                                                 int* __restrict__ off_dst,
                                                 int* __restrict__ list_src,
                                                 int* __restrict__ list_dst,
                                                 int N, int E) {
    __shared__ int cs[256], cd[256], wso[256], wdo[256], sh[256];
    const int tid = threadIdx.x;
    if (tid < 256) { cs[tid] = 0; cd[tid] = 0; }
    __syncthreads();
    for (int e = tid; e < E; e += 1024) {
        atomicAdd(&cs[eidx[e]], 1);
        atomicAdd(&cd[eidx[E + e]], 1);
    }
    __syncthreads();
    // exclusive scan of cs
    int orig_s = 0, orig_d = 0;
    if (tid < 256) { orig_s = (tid < N) ? cs[tid] : 0; sh[tid] = orig_s; }
    __syncthreads();
    for (int o = 1; o < 256; o <<= 1) {
        int v = 0;
        if (tid < 256 && tid >= o) v = sh[tid - o];
        __syncthreads();
        if (tid < 256) sh[tid] += v;
        __syncthreads();
    }
    if (tid < N) { int ex = sh[tid] - orig_s; off_src[tid] = ex; wso[tid] = ex; }
    if (tid == 0) off_src[N] = sh[255];
    __syncthreads();
    // exclusive scan of cd
    if (tid < 256) { orig_d = (tid < N) ? cd[tid] : 0; sh[tid] = orig_d; }
    __syncthreads();
    for (int o = 1; o < 256; o <<= 1) {
        int v = 0;
        if (tid < 256 && tid >= o) v = sh[tid - o];
        __syncthreads();
        if (tid < 256) sh[tid] += v;
        __syncthreads();
    }
    if (tid < N) { int ex = sh[tid] - orig_d; off_dst[tid] = ex; wdo[tid] = ex; }
    if (tid == 0) off_dst[N] = sh[255];
    __syncthreads();
    // fill packed lists: (other<<18)|(e<<1)|flag
    for (int e = tid; e < E; e += 1024) {
        int s = eidx[e], d = eidx[E + e];
        int ps = atomicAdd(&wso[s], 1);
        list_src[ps] = (d << 18) | (e << 1);
        int pd = atomicAdd(&wdo[d], 1);
        list_dst[pd] = (s << 18) | (e << 1) | 1;
    }
}

// ============================ main row kernel ==============================
template <int CPLX>
__global__ __launch_bounds__(256) void hr2hk_main(const float* __restrict__ ef,
                                                  const float* __restrict__ nf,
                                                  const float* __restrict__ kp,
                                                  const float* __restrict__ ecs,
                                                  const int*   __restrict__ off_src,
                                                  const int*   __restrict__ off_dst,
                                                  const int*   __restrict__ list_src,
                                                  const int*   __restrict__ list_dst,
                                                  float* __restrict__ out,
                                                  int N, int E, int K) {
    const int DIM  = N * 13;
    const int rowf = CPLX ? DIM * 2 : DIM;   // floats per output row (mult of 4, guarded)
    const int row4 = rowf >> 2;
    const int a   = blockIdx.x;              // output row index within a k-slice
    const int n1  = a / 13, r = a - n1 * 13;
    const int tid = threadIdx.x;

    constexpr int ROWM = CPLX ? 5200 : 2600;
    __shared__ float row[ROWM];
    __shared__ float h_sh[CAPC * 13];
    __shared__ float ph_sh[CAPC * KMAX * (CPLX ? 2 : 1)];
    __shared__ float ecs_sh[CAPC * 3];
    __shared__ int   lst[CAPC];
    __shared__ float dseg[13];
    __shared__ int   pm_s[13], pm_d[13];
    __shared__ float kp_sh[KMAX * 3];

    const int s0 = off_src[n1], ns = off_src[n1 + 1] - s0;
    const int d0 = off_dst[n1], nd = off_dst[n1 + 1] - d0;
    const int cnt = ns + nd;
    const bool fast = (cnt <= CAPC);

    if (tid < 13) {
        pm_s[tid] = pmap(r, tid);            // hop[r][c] source index
        pm_d[tid] = pmap(tid, r);            // hop[c][r] source index
        dseg[tid] = 0.5f * (nf[n1 * 107 + nmap(r, tid)] + nf[n1 * 107 + nmap(tid, r)]);
    }
    if (tid < K * 3) kp_sh[tid] = kp[tid];

    if (fast) {
        if (tid < cnt) lst[tid] = (tid < ns) ? list_src[s0 + tid]
                                             : list_dst[d0 + tid - ns];
        __syncthreads();
        // stage ecs per entry
        for (int t = tid; t < cnt * 3; t += 256) {
            int li = t / 3, x = t - li * 3;
            int e = ((unsigned)lst[li] >> 1) & 0x1FFFF;
            ecs_sh[t] = ecs[e * 3 + x];
        }
        __syncthreads();
        // stage phases (cos; cplx also sign-folded sin) for all (entry, k)
        for (int t = tid; t < cnt * K; t += 256) {
            int li = t / K, k = t - li * K;
            float dot = kp_sh[k * 3]     * ecs_sh[li * 3]
                      + kp_sh[k * 3 + 1] * ecs_sh[li * 3 + 1]
                      + kp_sh[k * 3 + 2] * ecs_sh[li * 3 + 2];
            float th = TWO_PI * dot;
            if (CPLX) {
                float sn, co;
                sincosf(th, &sn, &co);
                int flag = lst[li] & 1;
                ph_sh[(li * KMAX + k) * 2]     = co;
                ph_sh[(li * KMAX + k) * 2 + 1] = flag ? sn : -sn;
            } else {
                ph_sh[li * KMAX + k] = cosf(th);
            }
        }
        // stage hop 13-segments per entry
        for (int t = tid; t < cnt * 13; t += 256) {
            int li = t / 13, c = t - li * 13;
            int entry = lst[li];
            int e = ((unsigned)entry >> 1) & 0x1FFFF;
            h_sh[t] = ef[(long)e * 169 + ((entry & 1) ? pm_d[c] : pm_s[c])];
        }
    }
    __syncthreads();

    const float4 z = {0.f, 0.f, 0.f, 0.f};
    float4* r4 = (float4*)row;
    for (int k = 0; k < K; ++k) {
        // zero this k's row
        for (int t = tid; t < row4; t += 256) r4[t] = z;
        __syncthreads();
        // diagonal (atomic: self-loop edges may collide)
        if (tid < 13) {
            int col = n1 * 13 + tid;
            if (CPLX) atomicAdd(&row[col * 2], dseg[tid]);
            else      atomicAdd(&row[col], dseg[tid]);
        }
        if (fast) {
            for (int t = tid; t < cnt * 13; t += 256) {
                int li = t / 13, c = t - li * 13;
                int entry = lst[li];
                int other = (int)((unsigned)entry >> 18);
                int col = other * 13 + c;
                float h = h_sh[t];
                if (CPLX) {
                    float co = ph_sh[(li * KMAX + k) * 2];
                    float ss = ph_sh[(li * KMAX + k) * 2 + 1];
                    atomicAdd(&row[col * 2],     h * co);
                    atomicAdd(&row[col * 2 + 1], h * ss);
                } else {
                    atomicAdd(&row[col], h * ph_sh[li * KMAX + k]);
                }
            }
        } else {
            // degenerate-degree slow path: unstaged, correct for any cnt
            for (int t = tid; t < cnt * 13; t += 256) {
                int li = t / 13, c = t - li * 13;
                int entry = (li < ns) ? list_src[s0 + li] : list_dst[d0 + li - ns];
                int e     = ((unsigned)entry >> 1) & 0x1FFFF;
                int flag  = entry & 1;
                int other = (int)((unsigned)entry >> 18);
                float sx = ecs[e * 3], sy = ecs[e * 3 + 1], sz = ecs[e * 3 + 2];
                float dot = kp_sh[k * 3] * sx + kp_sh[k * 3 + 1] * sy + kp_sh[k * 3 + 2] * sz;
                float th = TWO_PI * dot;
                float h  = ef[(long)e * 169 + (flag ? pm_d[c] : pm_s[c])];
                int col = other * 13 + c;
                if (CPLX) {
                    float sn, co;
                    sincosf(th, &sn, &co);
                    atomicAdd(&row[col * 2],     h * co);
                    atomicAdd(&row[col * 2 + 1], flag ? h * sn : -h * sn);
                } else {
                    atomicAdd(&row[col], h * cosf(th));
                }
            }
        }
        __syncthreads();
        // stream the finished row out (written exactly once)
        long base = ((long)k * DIM + a) * (long)rowf;
        float4* o4 = (float4*)(out + base);
        for (int t = tid; t < row4; t += 256) o4[t] = r4[t];
        __syncthreads();   // LDS reads done before next k's zero
    }
}

// ====================== fallback path (round-3, verified) ==================

__global__ __launch_bounds__(256) void zero_kernel(float* __restrict__ out, long n) {
    long n4 = n >> 2;
    float4* out4 = (float4*)out;
    long i = (long)blockIdx.x * blockDim.x + threadIdx.x;
    long stride = (long)gridDim.x * blockDim.x;
    const float4 z = {0.f, 0.f, 0.f, 0.f};
    for (long t = i; t < n4; t += stride) out4[t] = z;
    if (i == 0) for (long j = n4 << 2; j < n; ++j) out[j] = 0.f;
}

template <int CPLX>
__global__ __launch_bounds__(256) void diag_kernel(const float* __restrict__ nf,
                                                   float* __restrict__ out,
                                                   int N, int total, long out_lim) {
    int t = blockIdx.x * blockDim.x + threadIdx.x;
    if (t >= total) return;
    int per_k = N * 169;
    int k = t / per_k, rem = t - k * per_k;
    int n = rem / 169, idx = rem - n * 169;
    int r = idx / 13, c = idx - r * 13;
    float v = 0.5f * (nf[n * 107 + nmap(r, c)] + nf[n * 107 + nmap(c, r)]);
    long DIM = (long)N * 13;
    long off = ((long)k * DIM + (long)n * 13 + r) * DIM + (long)n * 13 + c;
    if (CPLX) off *= 2;
    if (off >= 0 && off < out_lim) out[off] = v;
}

template <int CPLX>
__global__ __launch_bounds__(256) void edge_kernel(const float* __restrict__ ef,
                                                   const float* __restrict__ kp,
                                                   const float* __restrict__ ecs,
                                                   const int*   __restrict__ eidx,
                                                   float* __restrict__ out,
                                                   int N, int E, int K, long out_lim) {
    const int e = blockIdx.x;
    __shared__ float hop_sh[169];
    __shared__ float cos_sh[32];
    __shared__ float sin_sh[32];
    const int tid = threadIdx.x;
    const int r = tid / 13, c = tid - r * 13;

    if (tid < 169) hop_sh[tid] = ef[(long)e * 169 + pmap(r, c)];
    if (tid < K && tid < 32) {
        float sx = ecs[e * 3 + 0], sy = ecs[e * 3 + 1], sz = ecs[e * 3 + 2];
        float dot = kp[tid * 3 + 0] * sx + kp[tid * 3 + 1] * sy + kp[tid * 3 + 2] * sz;
        float th = TWO_PI * dot;
        float s, co;
        sincosf(th, &s, &co);
        cos_sh[tid] = co;
        sin_sh[tid] = s;
    }
    __syncthreads();
    if (tid >= 169) return;

    const int src = eidx[e];
    const int dst = eidx[E + e];
    const long DIM = (long)N * 13;
    const long SL  = DIM * DIM;
    const float h  = hop_sh[tid];
    const float ht = hop_sh[c * 13 + r];
    const long base1 = ((long)src * 13 + r) * DIM + (long)dst * 13 + c;
    const long base2 = ((long)dst * 13 + r) * DIM + (long)src * 13 + c;

    for (int k = 0; k < K; ++k) {
        float co = cos_sh[k & 31];
        float si = sin_sh[k & 31];
        if (CPLX) {
            long o1 = ((long)k * SL + base1) * 2;
            long o2 = ((long)k * SL + base2) * 2;
            if (o1 >= 0 && o1 + 1 < out_lim) {
                atomicAdd(out + o1,      h * co);
                atomicAdd(out + o1 + 1, -h * si);
            }
            if (o2 >= 0 && o2 + 1 < out_lim) {
                atomicAdd(out + o2,     ht * co);
                atomicAdd(out + o2 + 1, ht * si);
            }
        } else {
            long o1 = (long)k * SL + base1;
            long o2 = (long)k * SL + base2;
            if (o1 >= 0 && o1 < out_lim) atomicAdd(out + o1, h * co);
            if (o2 >= 0 && o2 < out_lim) atomicAdd(out + o2, ht * co);
        }
    }
}

// ================================ launch ===================================

extern "C" void kernel_launch(void* const* d_in, const int* in_sizes, int n_in,
                              void* d_out, int out_size, void* d_ws, size_t ws_size,
                              hipStream_t stream) {
    const float* ef   = (const float*)d_in[0];   // edge_features   (E, 169)
    const float* nf   = (const float*)d_in[1];   // node_features   (N, 107)
    const float* kp   = (const float*)d_in[2];   // kpoints         (K, 3)
    const float* ecs  = (const float*)d_in[3];   // edge_cell_shift (E, 3)
    const int*   eidx = (const int*)d_in[4];     // edge_index      (2, E)

    const int E = in_sizes[0] / 169;
    const int N = in_sizes[1] / 107;
    const int K = in_sizes[2] / 3;

    float* out = (float*)d_out;
    const long DIM  = (long)N * 13;
    const long SL   = DIM * DIM;
    const long full = (long)K * SL * 2;
    const int  cplx = ((long)out_size >= full) ? 1 : 0;
    const long out_lim = (long)out_size;

    const int  rowf = (int)DIM * (cplx ? 2 : 1);
    // ws: off_src[N+1] | off_dst[N+1] | list_src[E] | list_dst[E]
    const long ws_ints = 2L * (N + 1) + 2L * E;
    const bool fast_ok = (N >= 1) && (N <= 200) && (K >= 1) && (K <= KMAX) &&
                         (E >= 1) && (E < 131072) && (rowf % 4 == 0) &&
                         (ws_size >= (size_t)(ws_ints * 4)) &&
                         ((long)out_size == (long)K * SL * (cplx ? 2 : 1));

    if (fast_ok) {
        int* wi = (int*)d_ws;
        int* off_src  = wi;
        int* off_dst  = off_src + (N + 1);
        int* list_src = off_dst + (N + 1);
        int* list_dst = list_src + E;

        prep_all<<<1, 1024, 0, stream>>>(eidx, off_src, off_dst,
                                         list_src, list_dst, N, E);
        if (cplx)
            hr2hk_main<1><<<(int)DIM, 256, 0, stream>>>(ef, nf, kp, ecs,
                                                        off_src, off_dst,
                                                        list_src, list_dst,
                                                        out, N, E, K);
        else
            hr2hk_main<0><<<(int)DIM, 256, 0, stream>>>(ef, nf, kp, ecs,
                                                        off_src, off_dst,
                                                        list_src, list_dst,
                                                        out, N, E, K);
    } else {
        // verified round-3 fallback
        zero_kernel<<<2048, 256, 0, stream>>>(out, out_lim);
        int total_diag = K * N * 169;
        int blocks_diag = (total_diag + 255) / 256;
        if (cplx) {
            diag_kernel<1><<<blocks_diag, 256, 0, stream>>>(nf, out, N, total_diag, out_lim);
            edge_kernel<1><<<E, 256, 0, stream>>>(ef, kp, ecs, eidx, out, N, E, K, out_lim);
        } else {
            diag_kernel<0><<<blocks_diag, 256, 0, stream>>>(nf, out, N, total_diag, out_lim);
            edge_kernel<0><<<E, 256, 0, stream>>>(ef, kp, ecs, eidx, out, N, E, K, out_lim);
        }
    }
}

// Round 7
// 71.795 us; speedup vs baseline: 1.9491x; 1.5452x over previous
//
#include <hip/hip_runtime.h>

// ---------------------------------------------------------------------------
// HR2HK: H[k, N*13, N*13] from edge/node features, Hermitian fold-in.
// Three launches:
//  zero_cnt / bucket_fill: per-node incident-entry buckets via global atomics
//    (packed (other<<18)|(e<<1)|flag). No CSR, no scan, fully parallel.
//  hr2hk_main (kgroups*DIM blocks): block (a=n1*13+r, kg) stages its <=192
//    incident entries ONCE (hop 13-segments, phases, chain index by other-
//    node), then a BARRIER-FREE k-loop where each thread GATHER-computes its
//    owned float4 of the output row and streams it out. No LDS row buffer,
//    no atomics, no per-k barriers -> stores pipeline across the whole block.
// Dual layout keyed off out_size (proven round 3):
//   out_size >= 2*K*DIM^2 : interleaved complex64 ; else real-part-only f32.
// Node-degree overflow -> correct in-block global-atomic path (never taken).
// Guard failure -> verified round-3 3-kernel fallback.
// ---------------------------------------------------------------------------

// orbital structure: l = [0,0,1,1,2], sizes {1,1,3,3,5}, offsets {0,1,2,5,8}
__device__ __forceinline__ void orb_of(int r, int& i, int& ri, int& nv) {
    if (r < 1)      { i = 0; ri = r;     nv = 1; }
    else if (r < 2) { i = 1; ri = r - 1; nv = 1; }
    else if (r < 5) { i = 2; ri = r - 2; nv = 3; }
    else if (r < 8) { i = 3; ri = r - 5; nv = 3; }
    else            { i = 4; ri = r - 8; nv = 5; }
}
__device__ __forceinline__ int offs_of(int i) {
    return i == 0 ? 0 : (i == 1 ? 1 : (i == 2 ? 2 : (i == 3 ? 5 : 8)));
}
__device__ __forceinline__ int rowstart_of(int i) {   // {0,13,25,58,82}
    return i == 0 ? 0 : (i == 1 ? 13 : (i == 2 ? 25 : (i == 3 ? 58 : 82)));
}
__device__ __forceinline__ int pmap(int r, int c) {
    int i, ri, nvi, j, cj, nvj;
    orb_of(r, i, ri, nvi);
    orb_of(c, j, cj, nvj);
    return 13 * offs_of(i) + nvi * offs_of(j) + ri * nvj + cj;
}
__device__ __forceinline__ int nmap(int r, int c) {
    int i, ri, nvi, j, cj, nvj;
    orb_of(r, i, ri, nvi);
    orb_of(c, j, cj, nvj);
    if (i <= j)
        return rowstart_of(i) + nvi * (offs_of(j) - offs_of(i)) + ri * nvj + cj;
    else
        return rowstart_of(j) + nvj * (offs_of(i) - offs_of(j)) + cj * nvi + ri;
}

constexpr float TWO_PI = 6.28318530717958647692f;
constexpr int CAPC = 192;   // per-node incident-entry capacity

// ========================= prep: per-node buckets ==========================
__global__ __launch_bounds__(256) void zero_cnt(int* __restrict__ cnt, int N) {
    int t = threadIdx.x;
    if (t < N) cnt[t] = 0;
}

__global__ __launch_bounds__(256) void bucket_fill(const int* __restrict__ eidx,
                                                   int* __restrict__ cnt,
                                                   int* __restrict__ bkt,
                                                   int E) {
    int e = blockIdx.x * 256 + threadIdx.x;
    if (e >= E) return;
    int s = eidx[e], d = eidx[E + e];
    int p = atomicAdd(&cnt[s], 1);
    if (p < CAPC) bkt[s * CAPC + p] = (d << 18) | (e << 1);
    int q = atomicAdd(&cnt[d], 1);
    if (q < CAPC) bkt[d * CAPC + q] = (s << 18) | (e << 1) | 1;
}

// ============================ main row kernel ==============================
// block = (kg, a): gather-computes rows a of k-slices [kg*KB, kg*KB+kb).
template <int CPLX, int KB>
__global__ __launch_bounds__(256) void hr2hk_main(const float* __restrict__ ef,
                                                  const float* __restrict__ nf,
                                                  const float* __restrict__ kp,
                                                  const float* __restrict__ ecs,
                                                  const int*   __restrict__ eidx,
                                                  const int*   __restrict__ cnt,
                                                  const int*   __restrict__ bkt,
                                                  float* __restrict__ out,
                                                  int N, int E, int K) {
    const int DIM  = N * 13;
    const int rowf = CPLX ? DIM * 2 : DIM;   // floats per row (mult of 4, guarded)
    const int row4 = rowf >> 2;
    const int a   = blockIdx.x % DIM;
    const int kg  = blockIdx.x / DIM;
    const int n1  = a / 13, r = a - n1 * 13;
    const int k0  = kg * KB;
    const int kb  = (K - k0 < KB) ? (K - k0) : KB;
    const int tid = threadIdx.x;

    __shared__ float h_sh[CAPC * 13];
    __shared__ float ph_sh[CAPC * KB * (CPLX ? 2 : 1)];
    __shared__ float ecs_sh[CAPC * 3];
    __shared__ int   lst[CAPC];
    __shared__ int   head[256];
    __shared__ int   nxt[CAPC];
    __shared__ float dseg[13];
    __shared__ int   pm_s[13], pm_d[13];
    __shared__ float kp_sh[KB * 3];

    const int cnt_n = cnt[n1];
    const int cb = (cnt_n > CAPC) ? 0 : cnt_n;   // overflow -> gather path off

    head[tid & 255] = -1;
    if (tid < 13) {
        pm_s[tid] = pmap(r, tid);
        pm_d[tid] = pmap(tid, r);
        dseg[tid] = 0.5f * (nf[n1 * 107 + nmap(r, tid)] + nf[n1 * 107 + nmap(tid, r)]);
    }
    if (tid < kb * 3) kp_sh[tid] = kp[k0 * 3 + tid];
    if (tid < cb) lst[tid] = bkt[n1 * CAPC + tid];
    __syncthreads();

    if (tid < cb) {
        int o = (int)((unsigned)lst[tid] >> 18);
        nxt[tid] = atomicExch(&head[o], tid);
    }
    for (int t = tid; t < cb * 3; t += 256) {
        int li = t / 3, x = t - li * 3;
        int e = (int)(((unsigned)lst[li] >> 1) & 0x1FFFF);
        ecs_sh[t] = ecs[e * 3 + x];
    }
    __syncthreads();

    for (int t = tid; t < cb * kb; t += 256) {
        int li = t / kb, kk = t - li * kb;
        float dot = kp_sh[kk * 3]     * ecs_sh[li * 3]
                  + kp_sh[kk * 3 + 1] * ecs_sh[li * 3 + 1]
                  + kp_sh[kk * 3 + 2] * ecs_sh[li * 3 + 2];
        float th = TWO_PI * dot;
        if (CPLX) {
            float sn, co;
            sincosf(th, &sn, &co);
            int flag = lst[li] & 1;
            ph_sh[(li * KB + kk) * 2]     = co;
            ph_sh[(li * KB + kk) * 2 + 1] = flag ? sn : -sn;   // sign pre-folded
        } else {
            ph_sh[li * KB + kk] = cosf(th);
        }
    }
    for (int t = tid; t < cb * 13; t += 256) {
        int li = t / 13, c = t - li * 13;
        int entry = lst[li];
        int e = (int)(((unsigned)entry >> 1) & 0x1FFFF);
        h_sh[li * 13 + c] = ef[(long)e * 169 + ((entry & 1) ? pm_d[c] : pm_s[c])];
    }
    __syncthreads();

    // ---- barrier-free streaming: gather-compute owned float4s, store ----
    for (int kk = 0; kk < kb; ++kk) {
        long base = ((long)(k0 + kk) * DIM + a) * (long)rowf;
        float4* o4 = (float4*)(out + base);
        for (int t = tid; t < row4; t += 256) {
            float4 v;
            if (CPLX) {
#pragma unroll
                for (int j = 0; j < 2; ++j) {
                    int col = 2 * t + j;
                    int o = (int)((unsigned)col / 13u);
                    int cc = col - o * 13;
                    float re = (o == n1) ? dseg[cc] : 0.f;
                    float im = 0.f;
                    for (int li = head[o]; li >= 0; li = nxt[li]) {
                        float h = h_sh[li * 13 + cc];
                        re += h * ph_sh[(li * KB + kk) * 2];
                        im += h * ph_sh[(li * KB + kk) * 2 + 1];
                    }
                    ((float*)&v)[2 * j]     = re;
                    ((float*)&v)[2 * j + 1] = im;
                }
            } else {
#pragma unroll
                for (int j = 0; j < 4; ++j) {
                    int col = 4 * t + j;
                    int o = (int)((unsigned)col / 13u);
                    int cc = col - o * 13;
                    float val = (o == n1) ? dseg[cc] : 0.f;
                    for (int li = head[o]; li >= 0; li = nxt[li])
                        val += h_sh[li * 13 + cc] * ph_sh[li * KB + kk];
                    ((float*)&v)[j] = val;
                }
            }
            o4[t] = v;
        }
    }

    // ---- degenerate overflow path (cnt_n > CAPC): rows above hold diag+zeros;
    //      add every incident edge via global atomics (block-uniform branch) ----
    if (cnt_n > CAPC) {
        __syncthreads();   // stores visible at L2 before atomic RMW
        for (int t = tid; t < 2 * E; t += 256) {
            int e = t >> 1, side = t & 1;
            int node  = side ? eidx[E + e] : eidx[e];
            if (node != n1) continue;
            int other = side ? eidx[e] : eidx[E + e];
            float sx = ecs[e * 3], sy = ecs[e * 3 + 1], sz = ecs[e * 3 + 2];
            for (int kk = 0; kk < kb; ++kk) {
                float dot = kp_sh[kk * 3] * sx + kp_sh[kk * 3 + 1] * sy
                          + kp_sh[kk * 3 + 2] * sz;
                float th = TWO_PI * dot;
                long base = ((long)(k0 + kk) * DIM + a) * (long)rowf;
                if (CPLX) {
                    float sn, co;
                    sincosf(th, &sn, &co);
                    for (int c = 0; c < 13; ++c) {
                        float h = ef[(long)e * 169 + (side ? pm_d[c] : pm_s[c])];
                        atomicAdd(out + base + (other * 13 + c) * 2,     h * co);
                        atomicAdd(out + base + (other * 13 + c) * 2 + 1, side ? h * sn : -h * sn);
                    }
                } else {
                    float co = cosf(th);
                    for (int c = 0; c < 13; ++c) {
                        float h = ef[(long)e * 169 + (side ? pm_d[c] : pm_s[c])];
                        atomicAdd(out + base + other * 13 + c, h * co);
                    }
                }
            }
        }
    }
}

// ====================== fallback path (round-3, verified) ==================

__global__ __launch_bounds__(256) void zero_kernel(float* __restrict__ out, long n) {
    long n4 = n >> 2;
    float4* out4 = (float4*)out;
    long i = (long)blockIdx.x * blockDim.x + threadIdx.x;
    long stride = (long)gridDim.x * blockDim.x;
    const float4 z = {0.f, 0.f, 0.f, 0.f};
    for (long t = i; t < n4; t += stride) out4[t] = z;
    if (i == 0) for (long j = n4 << 2; j < n; ++j) out[j] = 0.f;
}

template <int CPLX>
__global__ __launch_bounds__(256) void diag_kernel(const float* __restrict__ nf,
                                                   float* __restrict__ out,
                                                   int N, int total, long out_lim) {
    int t = blockIdx.x * blockDim.x + threadIdx.x;
    if (t >= total) return;
    int per_k = N * 169;
    int k = t / per_k, rem = t - k * per_k;
    int n = rem / 169, idx = rem - n * 169;
    int r = idx / 13, c = idx - r * 13;
    float v = 0.5f * (nf[n * 107 + nmap(r, c)] + nf[n * 107 + nmap(c, r)]);
    long DIM = (long)N * 13;
    long off = ((long)k * DIM + (long)n * 13 + r) * DIM + (long)n * 13 + c;
    if (CPLX) off *= 2;
    if (off >= 0 && off < out_lim) out[off] = v;
}

template <int CPLX>
__global__ __launch_bounds__(256) void edge_kernel(const float* __restrict__ ef,
                                                   const float* __restrict__ kp,
                                                   const float* __restrict__ ecs,
                                                   const int*   __restrict__ eidx,
                                                   float* __restrict__ out,
                                                   int N, int E, int K, long out_lim) {
    const int e = blockIdx.x;
    __shared__ float hop_sh[169];
    __shared__ float cos_sh[32];
    __shared__ float sin_sh[32];
    const int tid = threadIdx.x;
    const int r = tid / 13, c = tid - r * 13;

    if (tid < 169) hop_sh[tid] = ef[(long)e * 169 + pmap(r, c)];
    if (tid < K && tid < 32) {
        float sx = ecs[e * 3 + 0], sy = ecs[e * 3 + 1], sz = ecs[e * 3 + 2];
        float dot = kp[tid * 3 + 0] * sx + kp[tid * 3 + 1] * sy + kp[tid * 3 + 2] * sz;
        float th = TWO_PI * dot;
        float s, co;
        sincosf(th, &s, &co);
        cos_sh[tid] = co;
        sin_sh[tid] = s;
    }
    __syncthreads();
    if (tid >= 169) return;

    const int src = eidx[e];
    const int dst = eidx[E + e];
    const long DIM = (long)N * 13;
    const long SL  = DIM * DIM;
    const float h  = hop_sh[tid];
    const float ht = hop_sh[c * 13 + r];
    const long base1 = ((long)src * 13 + r) * DIM + (long)dst * 13 + c;
    const long base2 = ((long)dst * 13 + r) * DIM + (long)src * 13 + c;

    for (int k = 0; k < K; ++k) {
        float co = cos_sh[k & 31];
        float si = sin_sh[k & 31];
        if (CPLX) {
            long o1 = ((long)k * SL + base1) * 2;
            long o2 = ((long)k * SL + base2) * 2;
            if (o1 >= 0 && o1 + 1 < out_lim) {
                atomicAdd(out + o1,      h * co);
                atomicAdd(out + o1 + 1, -h * si);
            }
            if (o2 >= 0 && o2 + 1 < out_lim) {
                atomicAdd(out + o2,     ht * co);
                atomicAdd(out + o2 + 1, ht * si);
            }
        } else {
            long o1 = (long)k * SL + base1;
            long o2 = (long)k * SL + base2;
            if (o1 >= 0 && o1 < out_lim) atomicAdd(out + o1, h * co);
            if (o2 >= 0 && o2 < out_lim) atomicAdd(out + o2, ht * co);
        }
    }
}

// ================================ launch ===================================

extern "C" void kernel_launch(void* const* d_in, const int* in_sizes, int n_in,
                              void* d_out, int out_size, void* d_ws, size_t ws_size,
                              hipStream_t stream) {
    const float* ef   = (const float*)d_in[0];   // edge_features   (E, 169)
    const float* nf   = (const float*)d_in[1];   // node_features   (N, 107)
    const float* kp   = (const float*)d_in[2];   // kpoints         (K, 3)
    const float* ecs  = (const float*)d_in[3];   // edge_cell_shift (E, 3)
    const int*   eidx = (const int*)d_in[4];     // edge_index      (2, E)

    const int E = in_sizes[0] / 169;
    const int N = in_sizes[1] / 107;
    const int K = in_sizes[2] / 3;

    float* out = (float*)d_out;
    const long DIM  = (long)N * 13;
    const long SL   = DIM * DIM;
    const long full = (long)K * SL * 2;
    const int  cplx = ((long)out_size >= full) ? 1 : 0;
    const long out_lim = (long)out_size;

    const int  rowf = (int)DIM * (cplx ? 2 : 1);
    // ws: cnt[N] | bkt[N*CAPC]   (ints)
    const long ws_ints = (long)N + (long)N * CAPC;
    const bool fast_ok = (N >= 1) && (N <= 256) && (K >= 1) &&
                         (E >= 1) && (E < 131072) && (rowf % 4 == 0) &&
                         (ws_size >= (size_t)(ws_ints * 4)) &&
                         ((long)out_size == (long)K * SL * (cplx ? 2 : 1));

    if (fast_ok) {
        int* cnt = (int*)d_ws;
        int* bkt = cnt + N;

        zero_cnt<<<1, 256, 0, stream>>>(cnt, N);
        bucket_fill<<<(E + 255) / 256, 256, 0, stream>>>(eidx, cnt, bkt, E);

        if (cplx) {
            constexpr int KB = 2;
            int kgroups = (K + KB - 1) / KB;
            hr2hk_main<1, KB><<<kgroups * (int)DIM, 256, 0, stream>>>(
                ef, nf, kp, ecs, eidx, cnt, bkt, out, N, E, K);
        } else {
            constexpr int KB = 4;
            int kgroups = (K + KB - 1) / KB;
            hr2hk_main<0, KB><<<kgroups * (int)DIM, 256, 0, stream>>>(
                ef, nf, kp, ecs, eidx, cnt, bkt, out, N, E, K);
        }
    } else {
        // verified round-3 fallback
        zero_kernel<<<2048, 256, 0, stream>>>(out, out_lim);
        int total_diag = K * N * 169;
        int blocks_diag = (total_diag + 255) / 256;
        if (cplx) {
            diag_kernel<1><<<blocks_diag, 256, 0, stream>>>(nf, out, N, total_diag, out_lim);
            edge_kernel<1><<<E, 256, 0, stream>>>(ef, kp, ecs, eidx, out, N, E, K, out_lim);
        } else {
            diag_kernel<0><<<blocks_diag, 256, 0, stream>>>(nf, out, N, total_diag, out_lim);
            edge_kernel<0><<<E, 256, 0, stream>>>(ef, kp, ecs, eidx, out, N, E, K, out_lim);
        }
    }
}

// Round 8
// 54.728 us; speedup vs baseline: 2.5569x; 1.3119x over previous
//
#include <hip/hip_runtime.h>

// ---------------------------------------------------------------------------
// HR2HK: H[k, N*13, N*13] from edge/node features, Hermitian fold-in.
// Three launches:
//  zero_cnt / bucket_fill: per-node incident-entry buckets via global atomics
//    (packed (other<<18)|(e<<1)|flag). No CSR, no scan, fully parallel.
//  hr2hk_main (DIM blocks x kgroups): block (a=n1*13+r, kg) stages incident
//    entries ONCE (hop 13-segments, per-(entry,k) phases, chain index by
//    other-node), then a BARRIER-FREE stream loop: each thread walks the
//    chain ONCE per column-quad, accumulates ALL KB k-slices in registers
//    (static indexing), and issues KB coalesced float4 stores. Every output
//    byte written exactly once; no global atomics; k-redundant gather gone.
// Dual layout keyed off out_size (proven round 3):
//   out_size >= 2*K*DIM^2 : interleaved complex64 ; else real-part-only f32.
// Node-degree overflow -> correct in-block global-atomic path (never taken).
// Guard failure -> verified round-3 3-kernel fallback.
// ---------------------------------------------------------------------------

// orbital structure: l = [0,0,1,1,2], sizes {1,1,3,3,5}, offsets {0,1,2,5,8}
__device__ __forceinline__ void orb_of(int r, int& i, int& ri, int& nv) {
    if (r < 1)      { i = 0; ri = r;     nv = 1; }
    else if (r < 2) { i = 1; ri = r - 1; nv = 1; }
    else if (r < 5) { i = 2; ri = r - 2; nv = 3; }
    else if (r < 8) { i = 3; ri = r - 5; nv = 3; }
    else            { i = 4; ri = r - 8; nv = 5; }
}
__device__ __forceinline__ int offs_of(int i) {
    return i == 0 ? 0 : (i == 1 ? 1 : (i == 2 ? 2 : (i == 3 ? 5 : 8)));
}
__device__ __forceinline__ int rowstart_of(int i) {   // {0,13,25,58,82}
    return i == 0 ? 0 : (i == 1 ? 13 : (i == 2 ? 25 : (i == 3 ? 58 : 82)));
}
__device__ __forceinline__ int pmap(int r, int c) {
    int i, ri, nvi, j, cj, nvj;
    orb_of(r, i, ri, nvi);
    orb_of(c, j, cj, nvj);
    return 13 * offs_of(i) + nvi * offs_of(j) + ri * nvj + cj;
}
__device__ __forceinline__ int nmap(int r, int c) {
    int i, ri, nvi, j, cj, nvj;
    orb_of(r, i, ri, nvi);
    orb_of(c, j, cj, nvj);
    if (i <= j)
        return rowstart_of(i) + nvi * (offs_of(j) - offs_of(i)) + ri * nvj + cj;
    else
        return rowstart_of(j) + nvj * (offs_of(i) - offs_of(j)) + cj * nvi + ri;
}

constexpr float TWO_PI = 6.28318530717958647692f;
constexpr int CAPC = 192;   // per-node incident-entry capacity

// ========================= prep: per-node buckets ==========================
__global__ __launch_bounds__(256) void zero_cnt(int* __restrict__ cnt, int N) {
    int t = blockIdx.x * 256 + threadIdx.x;
    if (t < N) cnt[t] = 0;
}

__global__ __launch_bounds__(256) void bucket_fill(const int* __restrict__ eidx,
                                                   int* __restrict__ cnt,
                                                   int* __restrict__ bkt,
                                                   int E) {
    int e = blockIdx.x * 256 + threadIdx.x;
    if (e >= E) return;
    int s = eidx[e], d = eidx[E + e];
    int p = atomicAdd(&cnt[s], 1);
    if (p < CAPC) bkt[s * CAPC + p] = (d << 18) | (e << 1);
    int q = atomicAdd(&cnt[d], 1);
    if (q < CAPC) bkt[d * CAPC + q] = (s << 18) | (e << 1) | 1;
}

// ============================ main row kernel ==============================
// block = (kg, a): computes rows a of k-slices [kg*KB, kg*KB+kb) with the
// chain walked ONCE per column, k accumulated in registers.
template <int CPLX, int KB>
__global__ __launch_bounds__(256) void hr2hk_main(const float* __restrict__ ef,
                                                  const float* __restrict__ nf,
                                                  const float* __restrict__ kp,
                                                  const float* __restrict__ ecs,
                                                  const int*   __restrict__ eidx,
                                                  const int*   __restrict__ cnt,
                                                  const int*   __restrict__ bkt,
                                                  float* __restrict__ out,
                                                  int N, int E, int K) {
    const int DIM  = N * 13;
    const int rowf = CPLX ? DIM * 2 : DIM;   // floats per row (mult of 4, guarded)
    const int row4 = rowf >> 2;
    const int a   = blockIdx.x % DIM;
    const int kg  = blockIdx.x / DIM;
    const int n1  = a / 13, r = a - n1 * 13;
    const int k0  = kg * KB;
    const int kb  = (K - k0 < KB) ? (K - k0) : KB;
    const int tid = threadIdx.x;

    __shared__ float h_sh[CAPC * 13];
    __shared__ float ph_sh[CAPC * KB * (CPLX ? 2 : 1)];
    __shared__ float ecs_sh[CAPC * 3];
    __shared__ int   lst[CAPC];
    __shared__ int   head[256];
    __shared__ int   nxt[CAPC];
    __shared__ float dseg[13];
    __shared__ int   pm_s[13], pm_d[13];
    __shared__ float kp_sh[KB * 3];

    const int cnt_n = cnt[n1];
    const int cb = (cnt_n > CAPC) ? 0 : cnt_n;   // overflow -> gather path off

    head[tid & 255] = -1;
    if (tid < 13) {
        pm_s[tid] = pmap(r, tid);
        pm_d[tid] = pmap(tid, r);
        dseg[tid] = 0.5f * (nf[n1 * 107 + nmap(r, tid)] + nf[n1 * 107 + nmap(tid, r)]);
    }
    if (tid < kb * 3) kp_sh[tid] = kp[k0 * 3 + tid];
    if (tid < cb) lst[tid] = bkt[n1 * CAPC + tid];
    __syncthreads();

    if (tid < cb) {
        int o = (int)((unsigned)lst[tid] >> 18);
        nxt[tid] = atomicExch(&head[o], tid);
    }
    for (int t = tid; t < cb * 3; t += 256) {
        int li = t / 3, x = t - li * 3;
        int e = (int)(((unsigned)lst[li] >> 1) & 0x1FFFF);
        ecs_sh[t] = ecs[e * 3 + x];
    }
    __syncthreads();

    for (int t = tid; t < cb * kb; t += 256) {
        int li = t / kb, kk = t - li * kb;
        float dot = kp_sh[kk * 3]     * ecs_sh[li * 3]
                  + kp_sh[kk * 3 + 1] * ecs_sh[li * 3 + 1]
                  + kp_sh[kk * 3 + 2] * ecs_sh[li * 3 + 2];
        float th = TWO_PI * dot;
        if (CPLX) {
            float sn, co;
            sincosf(th, &sn, &co);
            int flag = lst[li] & 1;
            ph_sh[(li * KB + kk) * 2]     = co;
            ph_sh[(li * KB + kk) * 2 + 1] = flag ? sn : -sn;   // sign pre-folded
        } else {
            ph_sh[li * KB + kk] = cosf(th);
        }
    }
    for (int t = tid; t < cb * 13; t += 256) {
        int li = t / 13, c = t - li * 13;
        int entry = lst[li];
        int e = (int)(((unsigned)entry >> 1) & 0x1FFFF);
        h_sh[li * 13 + c] = ef[(long)e * 169 + ((entry & 1) ? pm_d[c] : pm_s[c])];
    }
    __syncthreads();

    // ---- barrier-free streaming: chain walked once per col, k in registers --
    for (int t = tid; t < row4; t += 256) {
        float acc[KB][4];                       // static indexing (unrolled)
        if (CPLX) {
#pragma unroll
            for (int j = 0; j < 2; ++j) {       // two complex cols per float4
                int col = 2 * t + j;
                int o = (int)((unsigned)col / 13u);
                int cc = col - o * 13;
                float dre = (o == n1) ? dseg[cc] : 0.f;
#pragma unroll
                for (int kk = 0; kk < KB; ++kk) {
                    acc[kk][2 * j]     = dre;
                    acc[kk][2 * j + 1] = 0.f;
                }
                for (int li = head[o]; li >= 0; li = nxt[li]) {
                    float h = h_sh[li * 13 + cc];
#pragma unroll
                    for (int kk = 0; kk < KB; ++kk) {
                        acc[kk][2 * j]     += h * ph_sh[(li * KB + kk) * 2];
                        acc[kk][2 * j + 1] += h * ph_sh[(li * KB + kk) * 2 + 1];
                    }
                }
            }
        } else {
#pragma unroll
            for (int j = 0; j < 4; ++j) {
                int col = 4 * t + j;
                int o = (int)((unsigned)col / 13u);
                int cc = col - o * 13;
                float d = (o == n1) ? dseg[cc] : 0.f;
#pragma unroll
                for (int kk = 0; kk < KB; ++kk) acc[kk][j] = d;
                for (int li = head[o]; li >= 0; li = nxt[li]) {
                    float h = h_sh[li * 13 + cc];
#pragma unroll
                    for (int kk = 0; kk < KB; ++kk)
                        acc[kk][j] += h * ph_sh[li * KB + kk];
                }
            }
        }
#pragma unroll
        for (int kk = 0; kk < KB; ++kk) {
            if (kk < kb) {
                long base = ((long)(k0 + kk) * DIM + a) * (long)rowf;
                float4 v = {acc[kk][0], acc[kk][1], acc[kk][2], acc[kk][3]};
                ((float4*)(out + base))[t] = v;
            }
        }
    }

    // ---- degenerate overflow path (cnt_n > CAPC): rows above hold diag+zeros;
    //      add every incident edge via global atomics (block-uniform branch) ----
    if (cnt_n > CAPC) {
        __syncthreads();
        for (int t = tid; t < 2 * E; t += 256) {
            int e = t >> 1, side = t & 1;
            int node  = side ? eidx[E + e] : eidx[e];
            if (node != n1) continue;
            int other = side ? eidx[e] : eidx[E + e];
            float sx = ecs[e * 3], sy = ecs[e * 3 + 1], sz = ecs[e * 3 + 2];
            for (int kk = 0; kk < kb; ++kk) {
                float dot = kp_sh[kk * 3] * sx + kp_sh[kk * 3 + 1] * sy
                          + kp_sh[kk * 3 + 2] * sz;
                float th = TWO_PI * dot;
                long base = ((long)(k0 + kk) * DIM + a) * (long)rowf;
                if (CPLX) {
                    float sn, co;
                    sincosf(th, &sn, &co);
                    for (int c = 0; c < 13; ++c) {
                        float h = ef[(long)e * 169 + (side ? pm_d[c] : pm_s[c])];
                        atomicAdd(out + base + (other * 13 + c) * 2,     h * co);
                        atomicAdd(out + base + (other * 13 + c) * 2 + 1, side ? h * sn : -h * sn);
                    }
                } else {
                    float co = cosf(th);
                    for (int c = 0; c < 13; ++c) {
                        float h = ef[(long)e * 169 + (side ? pm_d[c] : pm_s[c])];
                        atomicAdd(out + base + other * 13 + c, h * co);
                    }
                }
            }
        }
    }
}

// ====================== fallback path (round-3, verified) ==================

__global__ __launch_bounds__(256) void zero_kernel(float* __restrict__ out, long n) {
    long n4 = n >> 2;
    float4* out4 = (float4*)out;
    long i = (long)blockIdx.x * blockDim.x + threadIdx.x;
    long stride = (long)gridDim.x * blockDim.x;
    const float4 z = {0.f, 0.f, 0.f, 0.f};
    for (long t = i; t < n4; t += stride) out4[t] = z;
    if (i == 0) for (long j = n4 << 2; j < n; ++j) out[j] = 0.f;
}

template <int CPLX>
__global__ __launch_bounds__(256) void diag_kernel(const float* __restrict__ nf,
                                                   float* __restrict__ out,
                                                   int N, int total, long out_lim) {
    int t = blockIdx.x * blockDim.x + threadIdx.x;
    if (t >= total) return;
    int per_k = N * 169;
    int k = t / per_k, rem = t - k * per_k;
    int n = rem / 169, idx = rem - n * 169;
    int r = idx / 13, c = idx - r * 13;
    float v = 0.5f * (nf[n * 107 + nmap(r, c)] + nf[n * 107 + nmap(c, r)]);
    long DIM = (long)N * 13;
    long off = ((long)k * DIM + (long)n * 13 + r) * DIM + (long)n * 13 + c;
    if (CPLX) off *= 2;
    if (off >= 0 && off < out_lim) out[off] = v;
}

template <int CPLX>
__global__ __launch_bounds__(256) void edge_kernel(const float* __restrict__ ef,
                                                   const float* __restrict__ kp,
                                                   const float* __restrict__ ecs,
                                                   const int*   __restrict__ eidx,
                                                   float* __restrict__ out,
                                                   int N, int E, int K, long out_lim) {
    const int e = blockIdx.x;
    __shared__ float hop_sh[169];
    __shared__ float cos_sh[32];
    __shared__ float sin_sh[32];
    const int tid = threadIdx.x;
    const int r = tid / 13, c = tid - r * 13;

    if (tid < 169) hop_sh[tid] = ef[(long)e * 169 + pmap(r, c)];
    if (tid < K && tid < 32) {
        float sx = ecs[e * 3 + 0], sy = ecs[e * 3 + 1], sz = ecs[e * 3 + 2];
        float dot = kp[tid * 3 + 0] * sx + kp[tid * 3 + 1] * sy + kp[tid * 3 + 2] * sz;
        float th = TWO_PI * dot;
        float s, co;
        sincosf(th, &s, &co);
        cos_sh[tid] = co;
        sin_sh[tid] = s;
    }
    __syncthreads();
    if (tid >= 169) return;

    const int src = eidx[e];
    const int dst = eidx[E + e];
    const long DIM = (long)N * 13;
    const long SL  = DIM * DIM;
    const float h  = hop_sh[tid];
    const float ht = hop_sh[c * 13 + r];
    const long base1 = ((long)src * 13 + r) * DIM + (long)dst * 13 + c;
    const long base2 = ((long)dst * 13 + r) * DIM + (long)src * 13 + c;

    for (int k = 0; k < K; ++k) {
        float co = cos_sh[k & 31];
        float si = sin_sh[k & 31];
        if (CPLX) {
            long o1 = ((long)k * SL + base1) * 2;
            long o2 = ((long)k * SL + base2) * 2;
            if (o1 >= 0 && o1 + 1 < out_lim) {
                atomicAdd(out + o1,      h * co);
                atomicAdd(out + o1 + 1, -h * si);
            }
            if (o2 >= 0 && o2 + 1 < out_lim) {
                atomicAdd(out + o2,     ht * co);
                atomicAdd(out + o2 + 1, ht * si);
            }
        } else {
            long o1 = (long)k * SL + base1;
            long o2 = (long)k * SL + base2;
            if (o1 >= 0 && o1 < out_lim) atomicAdd(out + o1, h * co);
            if (o2 >= 0 && o2 < out_lim) atomicAdd(out + o2, ht * co);
        }
    }
}

// ================================ launch ===================================

extern "C" void kernel_launch(void* const* d_in, const int* in_sizes, int n_in,
                              void* d_out, int out_size, void* d_ws, size_t ws_size,
                              hipStream_t stream) {
    const float* ef   = (const float*)d_in[0];   // edge_features   (E, 169)
    const float* nf   = (const float*)d_in[1];   // node_features   (N, 107)
    const float* kp   = (const float*)d_in[2];   // kpoints         (K, 3)
    const float* ecs  = (const float*)d_in[3];   // edge_cell_shift (E, 3)
    const int*   eidx = (const int*)d_in[4];     // edge_index      (2, E)

    const int E = in_sizes[0] / 169;
    const int N = in_sizes[1] / 107;
    const int K = in_sizes[2] / 3;

    float* out = (float*)d_out;
    const long DIM  = (long)N * 13;
    const long SL   = DIM * DIM;
    const long full = (long)K * SL * 2;
    const int  cplx = ((long)out_size >= full) ? 1 : 0;
    const long out_lim = (long)out_size;

    const int  rowf = (int)DIM * (cplx ? 2 : 1);
    // ws: cnt[N] | bkt[N*CAPC]   (ints)
    const long ws_ints = (long)N + (long)N * CAPC;
    const bool fast_ok = (N >= 1) && (N <= 256) && (K >= 1) &&
                         (E >= 1) && (E < 131072) && (rowf % 4 == 0) &&
                         (ws_size >= (size_t)(ws_ints * 4)) &&
                         ((long)out_size == (long)K * SL * (cplx ? 2 : 1));

    if (fast_ok) {
        int* cnt = (int*)d_ws;
        int* bkt = cnt + N;

        zero_cnt<<<(N + 255) / 256, 256, 0, stream>>>(cnt, N);
        bucket_fill<<<(E + 255) / 256, 256, 0, stream>>>(eidx, cnt, bkt, E);

        if (cplx) {
            constexpr int KB = 4;
            int kgroups = (K + KB - 1) / KB;
            hr2hk_main<1, KB><<<kgroups * (int)DIM, 256, 0, stream>>>(
                ef, nf, kp, ecs, eidx, cnt, bkt, out, N, E, K);
        } else {
            constexpr int KB = 8;
            int kgroups = (K + KB - 1) / KB;
            hr2hk_main<0, KB><<<kgroups * (int)DIM, 256, 0, stream>>>(
                ef, nf, kp, ecs, eidx, cnt, bkt, out, N, E, K);
        }
    } else {
        // verified round-3 fallback
        zero_kernel<<<2048, 256, 0, stream>>>(out, out_lim);
        int total_diag = K * N * 169;
        int blocks_diag = (total_diag + 255) / 256;
        if (cplx) {
            diag_kernel<1><<<blocks_diag, 256, 0, stream>>>(nf, out, N, total_diag, out_lim);
            edge_kernel<1><<<E, 256, 0, stream>>>(ef, kp, ecs, eidx, out, N, E, K, out_lim);
        } else {
            diag_kernel<0><<<blocks_diag, 256, 0, stream>>>(nf, out, N, total_diag, out_lim);
            edge_kernel<0><<<E, 256, 0, stream>>>(ef, kp, ecs, eidx, out, N, E, K, out_lim);
        }
    }
}

// Round 9
// 54.274 us; speedup vs baseline: 2.5783x; 1.0084x over previous
//
#include <hip/hip_runtime.h>

// ---------------------------------------------------------------------------
// HR2HK: H[k, N*13, N*13] from edge/node features, Hermitian fold-in.
// Launch sequence:
//  hipMemsetAsync(cnt)  : clear per-node counters (memset graph node)
//  bucket_fill          : per-node incident-entry buckets via global atomics
//                         (packed (other<<18)|(e<<1)|flag). No CSR, no scan.
//  hr2hk_main (DIM x kgroups blocks): block (a=n1*13+r, kg) stages incident
//    entries ONCE (hop 13-segments, per-(entry,k) phases with ecs read
//    straight from L2, chain index by other-node; 2 barriers), then a
//    BARRIER-FREE stream loop: each thread walks the chain ONCE per
//    column-quad, accumulates ALL KB k-slices in registers (static
//    indexing), and issues KB coalesced float4 stores. Every output byte
//    written exactly once; no global atomics.
// Dual layout keyed off out_size (proven round 3):
//   out_size >= 2*K*DIM^2 : interleaved complex64 ; else real-part-only f32.
// Node-degree overflow -> correct in-block global-atomic path (never taken).
// Guard failure -> verified round-3 3-kernel fallback.
// ---------------------------------------------------------------------------

// orbital structure: l = [0,0,1,1,2], sizes {1,1,3,3,5}, offsets {0,1,2,5,8}
__device__ __forceinline__ void orb_of(int r, int& i, int& ri, int& nv) {
    if (r < 1)      { i = 0; ri = r;     nv = 1; }
    else if (r < 2) { i = 1; ri = r - 1; nv = 1; }
    else if (r < 5) { i = 2; ri = r - 2; nv = 3; }
    else if (r < 8) { i = 3; ri = r - 5; nv = 3; }
    else            { i = 4; ri = r - 8; nv = 5; }
}
__device__ __forceinline__ int offs_of(int i) {
    return i == 0 ? 0 : (i == 1 ? 1 : (i == 2 ? 2 : (i == 3 ? 5 : 8)));
}
__device__ __forceinline__ int rowstart_of(int i) {   // {0,13,25,58,82}
    return i == 0 ? 0 : (i == 1 ? 13 : (i == 2 ? 25 : (i == 3 ? 58 : 82)));
}
__device__ __forceinline__ int pmap(int r, int c) {
    int i, ri, nvi, j, cj, nvj;
    orb_of(r, i, ri, nvi);
    orb_of(c, j, cj, nvj);
    return 13 * offs_of(i) + nvi * offs_of(j) + ri * nvj + cj;
}
__device__ __forceinline__ int nmap(int r, int c) {
    int i, ri, nvi, j, cj, nvj;
    orb_of(r, i, ri, nvi);
    orb_of(c, j, cj, nvj);
    if (i <= j)
        return rowstart_of(i) + nvi * (offs_of(j) - offs_of(i)) + ri * nvj + cj;
    else
        return rowstart_of(j) + nvj * (offs_of(i) - offs_of(j)) + cj * nvi + ri;
}

constexpr float TWO_PI = 6.28318530717958647692f;
constexpr int CAPC = 128;   // per-node incident-entry capacity

// ========================= prep: per-node buckets ==========================
__global__ __launch_bounds__(256) void bucket_fill(const int* __restrict__ eidx,
                                                   int* __restrict__ cnt,
                                                   int* __restrict__ bkt,
                                                   int E) {
    int e = blockIdx.x * 256 + threadIdx.x;
    if (e >= E) return;
    int s = eidx[e], d = eidx[E + e];
    int p = atomicAdd(&cnt[s], 1);
    if (p < CAPC) bkt[s * CAPC + p] = (d << 18) | (e << 1);
    int q = atomicAdd(&cnt[d], 1);
    if (q < CAPC) bkt[d * CAPC + q] = (s << 18) | (e << 1) | 1;
}

// ============================ main row kernel ==============================
// block = (kg, a): computes rows a of k-slices [kg*KB, kg*KB+kb) with the
// chain walked ONCE per column, k accumulated in registers.
template <int CPLX, int KB>
__global__ __launch_bounds__(256) void hr2hk_main(const float* __restrict__ ef,
                                                  const float* __restrict__ nf,
                                                  const float* __restrict__ kp,
                                                  const float* __restrict__ ecs,
                                                  const int*   __restrict__ eidx,
                                                  const int*   __restrict__ cnt,
                                                  const int*   __restrict__ bkt,
                                                  float* __restrict__ out,
                                                  int N, int E, int K) {
    const int DIM  = N * 13;
    const int rowf = CPLX ? DIM * 2 : DIM;   // floats per row (mult of 4, guarded)
    const int row4 = rowf >> 2;
    const int a   = blockIdx.x % DIM;
    const int kg  = blockIdx.x / DIM;
    const int n1  = a / 13, r = a - n1 * 13;
    const int k0  = kg * KB;
    const int kb  = (K - k0 < KB) ? (K - k0) : KB;
    const int tid = threadIdx.x;

    __shared__ float h_sh[CAPC * 13];
    __shared__ float ph_sh[CAPC * KB * (CPLX ? 2 : 1)];
    __shared__ int   lst[CAPC];
    __shared__ int   head[256];
    __shared__ int   nxt[CAPC];
    __shared__ float dseg[13];
    __shared__ int   pm_s[13], pm_d[13];
    __shared__ float kp_sh[KB * 3];

    const int cnt_n = cnt[n1];
    const int cb = (cnt_n > CAPC) ? 0 : cnt_n;   // overflow -> gather path off

    head[tid & 255] = -1;
    if (tid < 13) {
        pm_s[tid] = pmap(r, tid);
        pm_d[tid] = pmap(tid, r);
        dseg[tid] = 0.5f * (nf[n1 * 107 + nmap(r, tid)] + nf[n1 * 107 + nmap(tid, r)]);
    }
    if (tid < kb * 3) kp_sh[tid] = kp[k0 * 3 + tid];
    if (tid < cb) lst[tid] = bkt[n1 * CAPC + tid];
    __syncthreads();

    // chain build + phases (ecs straight from L2) + hop staging, one barrier
    if (tid < cb) {
        int o = (int)((unsigned)lst[tid] >> 18);
        nxt[tid] = atomicExch(&head[o], tid);
    }
    for (int t = tid; t < cb * KB; t += 256) {
        int li = t / KB, kk = t - li * KB;
        if (kk < kb) {
            int entry = lst[li];
            int e = (int)(((unsigned)entry >> 1) & 0x1FFFF);
            float sx = ecs[e * 3], sy = ecs[e * 3 + 1], sz = ecs[e * 3 + 2];
            float dot = kp_sh[kk * 3]     * sx
                      + kp_sh[kk * 3 + 1] * sy
                      + kp_sh[kk * 3 + 2] * sz;
            float th = TWO_PI * dot;
            if (CPLX) {
                float sn, co;
                sincosf(th, &sn, &co);
                ph_sh[(li * KB + kk) * 2]     = co;
                ph_sh[(li * KB + kk) * 2 + 1] = (entry & 1) ? sn : -sn;  // pre-folded
            } else {
                ph_sh[li * KB + kk] = cosf(th);
            }
        }
    }
    for (int t = tid; t < cb * 13; t += 256) {
        int li = t / 13, c = t - li * 13;
        int entry = lst[li];
        int e = (int)(((unsigned)entry >> 1) & 0x1FFFF);
        h_sh[li * 13 + c] = ef[(long)e * 169 + ((entry & 1) ? pm_d[c] : pm_s[c])];
    }
    __syncthreads();

    // ---- barrier-free streaming: chain walked once per col, k in registers --
    for (int t = tid; t < row4; t += 256) {
        float acc[KB][4];                       // static indexing (unrolled)
        if (CPLX) {
#pragma unroll
            for (int j = 0; j < 2; ++j) {       // two complex cols per float4
                int col = 2 * t + j;
                int o = (int)((unsigned)col / 13u);
                int cc = col - o * 13;
                float dre = (o == n1) ? dseg[cc] : 0.f;
#pragma unroll
                for (int kk = 0; kk < KB; ++kk) {
                    acc[kk][2 * j]     = dre;
                    acc[kk][2 * j + 1] = 0.f;
                }
                for (int li = head[o]; li >= 0; li = nxt[li]) {
                    float h = h_sh[li * 13 + cc];
#pragma unroll
                    for (int kk = 0; kk < KB; ++kk) {
                        acc[kk][2 * j]     += h * ph_sh[(li * KB + kk) * 2];
                        acc[kk][2 * j + 1] += h * ph_sh[(li * KB + kk) * 2 + 1];
                    }
                }
            }
        } else {
#pragma unroll
            for (int j = 0; j < 4; ++j) {
                int col = 4 * t + j;
                int o = (int)((unsigned)col / 13u);
                int cc = col - o * 13;
                float d = (o == n1) ? dseg[cc] : 0.f;
#pragma unroll
                for (int kk = 0; kk < KB; ++kk) acc[kk][j] = d;
                for (int li = head[o]; li >= 0; li = nxt[li]) {
                    float h = h_sh[li * 13 + cc];
#pragma unroll
                    for (int kk = 0; kk < KB; ++kk)
                        acc[kk][j] += h * ph_sh[li * KB + kk];
                }
            }
        }
#pragma unroll
        for (int kk = 0; kk < KB; ++kk) {
            if (kk < kb) {
                long base = ((long)(k0 + kk) * DIM + a) * (long)rowf;
                float4 v = {acc[kk][0], acc[kk][1], acc[kk][2], acc[kk][3]};
                ((float4*)(out + base))[t] = v;
            }
        }
    }

    // ---- degenerate overflow path (cnt_n > CAPC): rows above hold diag+zeros;
    //      add every incident edge via global atomics (block-uniform branch) ----
    if (cnt_n > CAPC) {
        __syncthreads();
        for (int t = tid; t < 2 * E; t += 256) {
            int e = t >> 1, side = t & 1;
            int node  = side ? eidx[E + e] : eidx[e];
            if (node != n1) continue;
            int other = side ? eidx[e] : eidx[E + e];
            float sx = ecs[e * 3], sy = ecs[e * 3 + 1], sz = ecs[e * 3 + 2];
            for (int kk = 0; kk < kb; ++kk) {
                float dot = kp_sh[kk * 3] * sx + kp_sh[kk * 3 + 1] * sy
                          + kp_sh[kk * 3 + 2] * sz;
                float th = TWO_PI * dot;
                long base = ((long)(k0 + kk) * DIM + a) * (long)rowf;
                if (CPLX) {
                    float sn, co;
                    sincosf(th, &sn, &co);
                    for (int c = 0; c < 13; ++c) {
                        float h = ef[(long)e * 169 + (side ? pm_d[c] : pm_s[c])];
                        atomicAdd(out + base + (other * 13 + c) * 2,     h * co);
                        atomicAdd(out + base + (other * 13 + c) * 2 + 1, side ? h * sn : -h * sn);
                    }
                } else {
                    float co = cosf(th);
                    for (int c = 0; c < 13; ++c) {
                        float h = ef[(long)e * 169 + (side ? pm_d[c] : pm_s[c])];
                        atomicAdd(out + base + other * 13 + c, h * co);
                    }
                }
            }
        }
    }
}

// ====================== fallback path (round-3, verified) ==================

__global__ __launch_bounds__(256) void zero_kernel(float* __restrict__ out, long n) {
    long n4 = n >> 2;
    float4* out4 = (float4*)out;
    long i = (long)blockIdx.x * blockDim.x + threadIdx.x;
    long stride = (long)gridDim.x * blockDim.x;
    const float4 z = {0.f, 0.f, 0.f, 0.f};
    for (long t = i; t < n4; t += stride) out4[t] = z;
    if (i == 0) for (long j = n4 << 2; j < n; ++j) out[j] = 0.f;
}

template <int CPLX>
__global__ __launch_bounds__(256) void diag_kernel(const float* __restrict__ nf,
                                                   float* __restrict__ out,
                                                   int N, int total, long out_lim) {
    int t = blockIdx.x * blockDim.x + threadIdx.x;
    if (t >= total) return;
    int per_k = N * 169;
    int k = t / per_k, rem = t - k * per_k;
    int n = rem / 169, idx = rem - n * 169;
    int r = idx / 13, c = idx - r * 13;
    float v = 0.5f * (nf[n * 107 + nmap(r, c)] + nf[n * 107 + nmap(c, r)]);
    long DIM = (long)N * 13;
    long off = ((long)k * DIM + (long)n * 13 + r) * DIM + (long)n * 13 + c;
    if (CPLX) off *= 2;
    if (off >= 0 && off < out_lim) out[off] = v;
}

template <int CPLX>
__global__ __launch_bounds__(256) void edge_kernel(const float* __restrict__ ef,
                                                   const float* __restrict__ kp,
                                                   const float* __restrict__ ecs,
                                                   const int*   __restrict__ eidx,
                                                   float* __restrict__ out,
                                                   int N, int E, int K, long out_lim) {
    const int e = blockIdx.x;
    __shared__ float hop_sh[169];
    __shared__ float cos_sh[32];
    __shared__ float sin_sh[32];
    const int tid = threadIdx.x;
    const int r = tid / 13, c = tid - r * 13;

    if (tid < 169) hop_sh[tid] = ef[(long)e * 169 + pmap(r, c)];
    if (tid < K && tid < 32) {
        float sx = ecs[e * 3 + 0], sy = ecs[e * 3 + 1], sz = ecs[e * 3 + 2];
        float dot = kp[tid * 3 + 0] * sx + kp[tid * 3 + 1] * sy + kp[tid * 3 + 2] * sz;
        float th = TWO_PI * dot;
        float s, co;
        sincosf(th, &s, &co);
        cos_sh[tid] = co;
        sin_sh[tid] = s;
    }
    __syncthreads();
    if (tid >= 169) return;

    const int src = eidx[e];
    const int dst = eidx[E + e];
    const long DIM = (long)N * 13;
    const long SL  = DIM * DIM;
    const float h  = hop_sh[tid];
    const float ht = hop_sh[c * 13 + r];
    const long base1 = ((long)src * 13 + r) * DIM + (long)dst * 13 + c;
    const long base2 = ((long)dst * 13 + r) * DIM + (long)src * 13 + c;

    for (int k = 0; k < K; ++k) {
        float co = cos_sh[k & 31];
        float si = sin_sh[k & 31];
        if (CPLX) {
            long o1 = ((long)k * SL + base1) * 2;
            long o2 = ((long)k * SL + base2) * 2;
            if (o1 >= 0 && o1 + 1 < out_lim) {
                atomicAdd(out + o1,      h * co);
                atomicAdd(out + o1 + 1, -h * si);
            }
            if (o2 >= 0 && o2 + 1 < out_lim) {
                atomicAdd(out + o2,     ht * co);
                atomicAdd(out + o2 + 1, ht * si);
            }
        } else {
            long o1 = (long)k * SL + base1;
            long o2 = (long)k * SL + base2;
            if (o1 >= 0 && o1 < out_lim) atomicAdd(out + o1, h * co);
            if (o2 >= 0 && o2 < out_lim) atomicAdd(out + o2, ht * co);
        }
    }
}

// ================================ launch ===================================

extern "C" void kernel_launch(void* const* d_in, const int* in_sizes, int n_in,
                              void* d_out, int out_size, void* d_ws, size_t ws_size,
                              hipStream_t stream) {
    const float* ef   = (const float*)d_in[0];   // edge_features   (E, 169)
    const float* nf   = (const float*)d_in[1];   // node_features   (N, 107)
    const float* kp   = (const float*)d_in[2];   // kpoints         (K, 3)
    const float* ecs  = (const float*)d_in[3];   // edge_cell_shift (E, 3)
    const int*   eidx = (const int*)d_in[4];     // edge_index      (2, E)

    const int E = in_sizes[0] / 169;
    const int N = in_sizes[1] / 107;
    const int K = in_sizes[2] / 3;

    float* out = (float*)d_out;
    const long DIM  = (long)N * 13;
    const long SL   = DIM * DIM;
    const long full = (long)K * SL * 2;
    const int  cplx = ((long)out_size >= full) ? 1 : 0;
    const long out_lim = (long)out_size;

    const int  rowf = (int)DIM * (cplx ? 2 : 1);
    // ws: cnt[N] | bkt[N*CAPC]   (ints)
    const long ws_ints = (long)N + (long)N * CAPC;
    const bool fast_ok = (N >= 1) && (N <= 256) && (K >= 1) &&
                         (E >= 1) && (E < 131072) && (rowf % 4 == 0) &&
                         (ws_size >= (size_t)(ws_ints * 4)) &&
                         ((long)out_size == (long)K * SL * (cplx ? 2 : 1));

    if (fast_ok) {
        int* cnt = (int*)d_ws;
        int* bkt = cnt + N;

        hipMemsetAsync(cnt, 0, (size_t)N * sizeof(int), stream);
        bucket_fill<<<(E + 255) / 256, 256, 0, stream>>>(eidx, cnt, bkt, E);

        if (cplx) {
            constexpr int KB = 4;
            int kgroups = (K + KB - 1) / KB;
            hr2hk_main<1, KB><<<kgroups * (int)DIM, 256, 0, stream>>>(
                ef, nf, kp, ecs, eidx, cnt, bkt, out, N, E, K);
        } else {
            constexpr int KB = 8;
            int kgroups = (K + KB - 1) / KB;
            hr2hk_main<0, KB><<<kgroups * (int)DIM, 256, 0, stream>>>(
                ef, nf, kp, ecs, eidx, cnt, bkt, out, N, E, K);
        }
    } else {
        // verified round-3 fallback
        zero_kernel<<<2048, 256, 0, stream>>>(out, out_lim);
        int total_diag = K * N * 169;
        int blocks_diag = (total_diag + 255) / 256;
        if (cplx) {
            diag_kernel<1><<<blocks_diag, 256, 0, stream>>>(nf, out, N, total_diag, out_lim);
            edge_kernel<1><<<E, 256, 0, stream>>>(ef, kp, ecs, eidx, out, N, E, K, out_lim);
        } else {
            diag_kernel<0><<<blocks_diag, 256, 0, stream>>>(nf, out, N, total_diag, out_lim);
            edge_kernel<0><<<E, 256, 0, stream>>>(ef, kp, ecs, eidx, out, N, E, K, out_lim);
        }
    }
}